// Round 3
// baseline (300.705 us; speedup 1.0000x reference)
//
#include <hip/hip_runtime.h>
#include <climits>

typedef __attribute__((ext_vector_type(8))) short s8;      // 8 bf16 = 4 VGPRs
typedef __attribute__((ext_vector_type(4))) float f32x4;   // MFMA acc

#define BQ    256
#define DDIM  256
#define NBANK 100000
#define BN    64                          // bank cols per tile (4 col-tiles of 16)
#define NJB   ((NBANK + BN - 1) / BN)     // 1563
#define GRIDX 512                         // persistent blocks: 2 per CU exactly
#define SENT  1e30f

// Split fp32 x into bf16 hi (round-half-up) + bf16 lo: x ~= hi + lo, |err| <~ 2^-18|x|
__device__ inline void splitElem(float x, s8& h, s8& l, int i) {
    unsigned u  = __float_as_uint(x);
    unsigned uh = (u + 0x8000u) & 0xFFFF0000u;
    h[i] = (short)(uh >> 16);
    float lf = x - __uint_as_float(uh);            // exact
    l[i] = (short)((__float_as_uint(lf) + 0x8000u) >> 16);
}

__device__ inline void split8(const float4 v0, const float4 v1, s8& h, s8& l) {
    splitElem(v0.x, h, l, 0); splitElem(v0.y, h, l, 1);
    splitElem(v0.z, h, l, 2); splitElem(v0.w, h, l, 3);
    splitElem(v1.x, h, l, 4); splitElem(v1.y, h, l, 5);
    splitElem(v1.z, h, l, 6); splitElem(v1.w, h, l, 7);
}

__device__ inline float sq8(const float4 v0, const float4 v1, float s) {
    s = fmaf(v0.x, v0.x, s); s = fmaf(v0.y, v0.y, s);
    s = fmaf(v0.z, v0.z, s); s = fmaf(v0.w, v0.w, s);
    s = fmaf(v1.x, v1.x, s); s = fmaf(v1.y, v1.y, s);
    s = fmaf(v1.z, v1.z, s); s = fmaf(v1.w, v1.w, s);
    return s;
}

// Kernel 0: pre-split the tiny A (feature) into MFMA-A-fragment-ordered bf16 hi/lo.
__global__ __launch_bounds__(512) void split_feature(
    const float* __restrict__ feature, s8* __restrict__ fH, s8* __restrict__ fL)
{
    const int t    = blockIdx.x * 512 + threadIdx.x;   // 0..8191
    const int lane = t & 63, ks = (t >> 6) & 7, rt = t >> 9;
    const int row  = rt * 16 + (lane & 15);
    const int k0   = ks * 32 + (lane >> 4) * 8;
    const float* p = feature + (size_t)row * DDIM + k0;
    const float4 v0 = *(const float4*)p;
    const float4 v1 = *(const float4*)(p + 4);
    s8 h, l;
    split8(v0, v1, h, l);
    fH[t] = h; fL[t] = l;
}

// Kernel 1: PERSISTENT-BLOCK pipelined split-bf16 MFMA GEMM + fused masked argmin.
// Grid = 512 (2 blocks/CU), each block loops over tiles jb, jb+512, ... (~3 tiles).
// Pipeline per tile: stage(regs->LDS) | barrier | ISSUE next-tile global loads |
// MFMA compute | epilogue argmin | barrier. The next-tile loads sit in VGPRs and
// their ~900cy latency hides under ~6k cycles of compute+epilogue, so the
// barrier's vmcnt(0) drain is free. Cold staging latency paid 512x, not 1563x.
// LDS ds_write/ds_read XOR-swizzled by slice (^q / ^s) -> bank-quad spread,
// fixing the 8-way staging write conflict (5.6M conflict cycles in round 2).
__global__ __launch_bounds__(512, 4) void gemm_argmin_persist(
    const s8* __restrict__ fH, const s8* __restrict__ fL,
    const float* __restrict__ bank,
    const int* __restrict__ cluster_label, const int* __restrict__ class_label,
    const int* __restrict__ cluster_idx,  const int* __restrict__ gt_label,
    float* __restrict__ wsPV, int* __restrict__ wsPI,
    float* __restrict__ wsDV, int* __restrict__ wsDI)
{
    __shared__ __align__(16) s8 bHs[8 * 4 * 64];   // [s][ct][fraglane] 32 KB
    __shared__ __align__(16) s8 bLs[8 * 4 * 64];   // 32 KB
    __shared__ float b2s[BN];
    __shared__ int clsS[BN], cluS[BN], rowGt[BQ], rowClu[BQ];

    const int tid = threadIdx.x;
    if (tid < BQ) {
        rowGt[tid]  = gt_label[tid];
        rowClu[tid] = cluster_idx[tid];
    }

    // Staging role: col = tid>>3 (0..63), q = tid&7 (slice); 128 B contiguous/thread
    const int col = tid >> 3, q = tid & 7;
    const int ct_s = col >> 4, cl_s = col & 15;
    // Compute/epilogue role
    const int w = tid >> 6, lane = tid & 63;
    const int g = lane >> 4, c = lane & 15;

    int jb = blockIdx.x;

    // ---- Prologue: load tile jb into registers (the only cold staging latency)
    float4 v0[4], v1[4];
    int lblC = 0, lblU = 0;
    {
        int jcol = jb * BN + col; if (jcol >= NBANK) jcol = NBANK - 1;
        const float* gb = bank + (size_t)jcol * DDIM + q * 32;
        #pragma unroll
        for (int i = 0; i < 4; ++i) {
            v0[i] = *(const float4*)(gb + i * 8);
            v1[i] = *(const float4*)(gb + i * 8 + 4);
        }
        if (tid < BN) {
            int jg = jb * BN + tid; int jc = jg < NBANK ? jg : NBANK - 1;
            lblC = class_label[jc];
            lblU = cluster_label[jc];
        }
    }

    for (;;) {
        const int j0 = jb * BN;

        // ---- Stage current tile: split fp32 regs -> bf16 hi/lo frags in LDS
        float sqa = 0.f;
        #pragma unroll
        for (int i = 0; i < 4; ++i) {
            s8 h, l;
            split8(v0[i], v1[i], h, l);
            sqa = sq8(v0[i], v1[i], sqa);
            const int wi = ((q * 4 + ct_s) * 64 + i * 16 + cl_s) ^ q;  // swizzled
            bHs[wi] = h;
            bLs[wi] = l;
        }
        sqa += __shfl_xor(sqa, 1);
        sqa += __shfl_xor(sqa, 2);
        sqa += __shfl_xor(sqa, 4);
        if (q == 0) b2s[col] = sqa;
        if (tid < BN) { clsS[tid] = lblC; cluS[tid] = lblU; }
        __syncthreads();                   // staging visible

        // ---- Issue next-tile prefetch NOW; lands during compute+epilogue
        const int jbn = jb + GRIDX;
        const bool more = (jbn < NJB);
        if (more) {
            int jcol = jbn * BN + col; if (jcol >= NBANK) jcol = NBANK - 1;
            const float* gb = bank + (size_t)jcol * DDIM + q * 32;
            #pragma unroll
            for (int i = 0; i < 4; ++i) {
                v0[i] = *(const float4*)(gb + i * 8);
                v1[i] = *(const float4*)(gb + i * 8 + 4);
            }
            if (tid < BN) {
                int jg = jbn * BN + tid; int jc = jg < NBANK ? jg : NBANK - 1;
                lblC = class_label[jc];
                lblU = cluster_label[jc];
            }
        }

        // ---- Compute: wave w owns rows w*32..+31 (2 row-tiles); 256 MFMAs/wave
        f32x4 acc[4][2];
        #pragma unroll
        for (int ct = 0; ct < 4; ++ct)
            #pragma unroll
            for (int rt = 0; rt < 2; ++rt)
                acc[ct][rt] = (f32x4){0.f, 0.f, 0.f, 0.f};

        #pragma unroll
        for (int s = 0; s < 8; ++s) {
            s8 aH[2], aL[2];
            #pragma unroll
            for (int rt = 0; rt < 2; ++rt) {   // A frags from L2-resident fH/fL
                const int RT = w * 2 + rt;
                aH[rt] = fH[(RT * 8 + s) * 64 + lane];
                aL[rt] = fL[(RT * 8 + s) * 64 + lane];
            }
            #pragma unroll
            for (int ct = 0; ct < 4; ++ct) {
                const s8 bh = bHs[((s * 4 + ct) * 64 + lane) ^ s];     // swizzled
                const s8 bl = bLs[((s * 4 + ct) * 64 + lane) ^ s];
                #pragma unroll
                for (int rt = 0; rt < 2; ++rt) {
                    acc[ct][rt] = __builtin_amdgcn_mfma_f32_16x16x32_bf16(aH[rt], bh, acc[ct][rt], 0, 0, 0);
                    acc[ct][rt] = __builtin_amdgcn_mfma_f32_16x16x32_bf16(aH[rt], bl, acc[ct][rt], 0, 0, 0);
                    acc[ct][rt] = __builtin_amdgcn_mfma_f32_16x16x32_bf16(aL[rt], bh, acc[ct][rt], 0, 0, 0);
                    acc[ct][rt] = __builtin_amdgcn_mfma_f32_16x16x32_bf16(aL[rt], bl, acc[ct][rt], 0, 0, 0);
                }
            }
        }

        // ---- Epilogue: C/D layout col = lane&15, row = g*4 + reg (HW-verified)
        #pragma unroll
        for (int rt = 0; rt < 2; ++rt) {
            #pragma unroll
            for (int r = 0; r < 4; ++r) {
                const int row  = w * 32 + rt * 16 + g * 4 + r;
                const int myGt = rowGt[row], myClu = rowClu[row];
                float bpv = SENT, bdv = SENT;
                int   bpi = INT_MAX, bdi = INT_MAX;
                #pragma unroll
                for (int ct = 0; ct < 4; ++ct) {   // ascending ct = ascending col
                    const int jg = j0 + ct * 16 + c;
                    const float sc = b2s[ct * 16 + c] - 2.f * acc[ct][rt][r];
                    if (jg < NBANK && clsS[ct * 16 + c] != myGt) {
                        if (sc < bdv) { bdv = sc; bdi = jg; }
                        if (cluS[ct * 16 + c] == myClu && sc < bpv) { bpv = sc; bpi = jg; }
                    }
                }
                #pragma unroll
                for (int off = 1; off < 16; off <<= 1) {   // tie-aware 16-lane reduce
                    float vv = __shfl_xor(bpv, off); int ii = __shfl_xor(bpi, off);
                    if (vv < bpv || (vv == bpv && ii < bpi)) { bpv = vv; bpi = ii; }
                    vv = __shfl_xor(bdv, off); ii = __shfl_xor(bdi, off);
                    if (vv < bdv || (vv == bdv && ii < bdi)) { bdv = vv; bdi = ii; }
                }
                if (c == 0) {
                    const size_t o = (size_t)jb * BQ + row;   // [jb][row]: 1KB runs
                    wsPV[o] = bpv; wsPI[o] = bpi;
                    wsDV[o] = bdv; wsDI[o] = bdi;
                }
            }
        }
        __syncthreads();                   // all waves done with this tile's LDS
        if (!more) break;
        jb = jbn;
    }
}

// Kernel 2: per-row reduction over NJB partials (transposed layout), fallback
// select, gather bank row.
__global__ __launch_bounds__(256) void reduce_gather(
    const float* __restrict__ wsPV, const int* __restrict__ wsPI,
    const float* __restrict__ wsDV, const int* __restrict__ wsDI,
    const float* __restrict__ bank, float* __restrict__ out)
{
    const int row = blockIdx.x, tid = threadIdx.x;
    float bpv = SENT, bdv = SENT;
    int   bpi = INT_MAX, bdi = INT_MAX;
    for (int b = tid; b < NJB; b += 256) {
        const size_t o = (size_t)b * BQ + row;
        float v = wsPV[o]; int ix = wsPI[o];
        if (v < bpv || (v == bpv && ix < bpi)) { bpv = v; bpi = ix; }
        v = wsDV[o]; ix = wsDI[o];
        if (v < bdv || (v == bdv && ix < bdi)) { bdv = v; bdi = ix; }
    }
    #pragma unroll
    for (int off = 32; off > 0; off >>= 1) {
        float v = __shfl_down(bpv, off); int ix = __shfl_down(bpi, off);
        if (v < bpv || (v == bpv && ix < bpi)) { bpv = v; bpi = ix; }
        v = __shfl_down(bdv, off); ix = __shfl_down(bdi, off);
        if (v < bdv || (v == bdv && ix < bdi)) { bdv = v; bdi = ix; }
    }
    __shared__ float swPV[4], swDV[4];
    __shared__ int   swPI[4], swDI[4];
    __shared__ int   sIdx;
    const int lane = tid & 63, wv = tid >> 6;
    if (lane == 0) { swPV[wv] = bpv; swPI[wv] = bpi; swDV[wv] = bdv; swDI[wv] = bdi; }
    __syncthreads();
    if (tid == 0) {
        float pv = swPV[0]; int pi = swPI[0];
        float dv = swDV[0]; int di = swDI[0];
        #pragma unroll
        for (int w = 1; w < 4; ++w) {
            if (swPV[w] < pv || (swPV[w] == pv && swPI[w] < pi)) { pv = swPV[w]; pi = swPI[w]; }
            if (swDV[w] < dv || (swDV[w] == dv && swDI[w] < di)) { dv = swDV[w]; di = swDI[w]; }
        }
        sIdx = (pi != INT_MAX) ? pi : ((di != INT_MAX) ? di : 0);
    }
    __syncthreads();
    out[row * DDIM + tid] = bank[(size_t)sIdx * DDIM + tid];
}

extern "C" void kernel_launch(void* const* d_in, const int* in_sizes, int n_in,
                              void* d_out, int out_size, void* d_ws, size_t ws_size,
                              hipStream_t stream) {
    const float* feature       = (const float*)d_in[0];
    const float* bank          = (const float*)d_in[1];
    const int*   cluster_label = (const int*)d_in[2];
    const int*   class_label   = (const int*)d_in[3];
    const int*   cluster_idx   = (const int*)d_in[4];
    const int*   gt_label      = (const int*)d_in[5];
    float* out = (float*)d_out;

    // Workspace: fH/fL (128 KB each) + 4 partial arrays [NJB][256] (6.4 MB)
    s8* fH = (s8*)d_ws;                 // 8192 frags
    s8* fL = fH + 8192;
    float* base = (float*)((char*)d_ws + 2 * 8192 * sizeof(s8));
    const size_t per = (size_t)BQ * NJB;
    float* wsPV = base;
    int*   wsPI = (int*)base + per;
    float* wsDV = base + 2 * per;
    int*   wsDI = (int*)base + 3 * per;

    hipLaunchKernelGGL(split_feature, dim3(16), dim3(512), 0, stream, feature, fH, fL);
    hipLaunchKernelGGL(gemm_argmin_persist, dim3(GRIDX), dim3(512), 0, stream,
                       fH, fL, bank, cluster_label, class_label, cluster_idx, gt_label,
                       wsPV, wsPI, wsDV, wsDI);
    hipLaunchKernelGGL(reduce_gather, dim3(BQ), dim3(256), 0, stream,
                       wsPV, wsPI, wsDV, wsDI, bank, out);
}

// Round 4
// 289.107 us; speedup vs baseline: 1.0401x; 1.0401x over previous
//
#include <hip/hip_runtime.h>
#include <climits>

typedef __attribute__((ext_vector_type(8))) short s8;      // 8 bf16 = 4 VGPRs
typedef __attribute__((ext_vector_type(4))) float f32x4;   // MFMA acc

#define BQ    256
#define DDIM  256
#define NBANK 100000
#define BN    64                          // bank cols per tile (4 col-tiles of 16)
#define NJB   ((NBANK + BN - 1) / BN)     // 1563
#define SENT  1e30f

// Split fp32 x into bf16 hi (round-half-up) + bf16 lo: x ~= hi + lo, |err| <~ 2^-18|x|
__device__ inline void splitElem(float x, s8& h, s8& l, int i) {
    unsigned u  = __float_as_uint(x);
    unsigned uh = (u + 0x8000u) & 0xFFFF0000u;
    h[i] = (short)(uh >> 16);
    float lf = x - __uint_as_float(uh);            // exact
    l[i] = (short)((__float_as_uint(lf) + 0x8000u) >> 16);
}

__device__ inline void split8(const float4 v0, const float4 v1, s8& h, s8& l) {
    splitElem(v0.x, h, l, 0); splitElem(v0.y, h, l, 1);
    splitElem(v0.z, h, l, 2); splitElem(v0.w, h, l, 3);
    splitElem(v1.x, h, l, 4); splitElem(v1.y, h, l, 5);
    splitElem(v1.z, h, l, 6); splitElem(v1.w, h, l, 7);
}

__device__ inline float sq8(const float4 v0, const float4 v1, float s) {
    s = fmaf(v0.x, v0.x, s); s = fmaf(v0.y, v0.y, s);
    s = fmaf(v0.z, v0.z, s); s = fmaf(v0.w, v0.w, s);
    s = fmaf(v1.x, v1.x, s); s = fmaf(v1.y, v1.y, s);
    s = fmaf(v1.z, v1.z, s); s = fmaf(v1.w, v1.w, s);
    return s;
}

// Kernel 0: pre-split the tiny A (feature) into MFMA-A-fragment-ordered bf16 hi/lo.
__global__ __launch_bounds__(512) void split_feature(
    const float* __restrict__ feature, s8* __restrict__ fH, s8* __restrict__ fL)
{
    const int t    = blockIdx.x * 512 + threadIdx.x;   // 0..8191
    const int lane = t & 63, ks = (t >> 6) & 7, rt = t >> 9;
    const int row  = rt * 16 + (lane & 15);
    const int k0   = ks * 32 + (lane >> 4) * 8;
    const float* p = feature + (size_t)row * DDIM + k0;
    const float4 v0 = *(const float4*)p;
    const float4 v1 = *(const float4*)(p + 4);
    s8 h, l;
    split8(v0, v1, h, l);
    fH[t] = h; fL[t] = l;
}

// Kernel 1: HALF-K double-pass split-bf16 MFMA GEMM + fused masked argmin.
// OCCUPANCY-MAX: LDS holds only 4 k-slices (32 KB frags + ~3 KB labels = ~35 KB)
// -> 4 blocks/CU x 8 waves = 32 waves/CU (HW max), launch_bounds(512,8) caps
// VGPR at 256 (no spill). Non-persistent: no loop-carried register arrays for
// LLVM to demote to scratch (round-3 lesson: 167 MB of spill traffic).
// Pipeline: stage h0 | bar | issue h1 loads | compute s0..3 | bar | stage h1
// | bar | compute s4..7 | epilogue. h1's ~900cy load latency hides under
// compute0's 128 MFMAs.
__global__ __launch_bounds__(512, 8) void gemm_argmin_halfk(
    const s8* __restrict__ fH, const s8* __restrict__ fL,
    const float* __restrict__ bank,
    const int* __restrict__ cluster_label, const int* __restrict__ class_label,
    const int* __restrict__ cluster_idx,  const int* __restrict__ gt_label,
    float* __restrict__ wsPV, int* __restrict__ wsPI,
    float* __restrict__ wsDV, int* __restrict__ wsDI)
{
    __shared__ __align__(16) s8 bHs[4 * 4 * 64];   // [sl][ct][fraglane] 16 KB
    __shared__ __align__(16) s8 bLs[4 * 4 * 64];   // 16 KB
    __shared__ float b2s[BN];
    __shared__ int clsS[BN], cluS[BN], rowGt[BQ], rowClu[BQ];

    const int tid = threadIdx.x;
    const int jb  = blockIdx.x;
    const int j0  = jb * BN;

    // Staging role: col = tid>>3 (0..63), q = tid&7; per half: 64 B contiguous/thread
    const int col = tid >> 3, q = tid & 7;
    const int ct_s = col >> 4, cl_s = col & 15;
    const int sl_s = q >> 1, p_s = q & 1;          // slice-in-half, octet-pair
    // Compute/epilogue role
    const int w = tid >> 6, lane = tid & 63;
    const int g = lane >> 4, c = lane & 15;

    int jcol = j0 + col; if (jcol >= NBANK) jcol = NBANK - 1;
    const float* gb = bank + (size_t)jcol * DDIM + q * 16;   // +h*128 per half

    // ---- Prologue: labels + half-0 loads
    if (tid < BQ) {
        rowGt[tid]  = gt_label[tid];
        rowClu[tid] = cluster_idx[tid];
    }
    if (tid < BN) {
        int jg = j0 + tid; int jc = jg < NBANK ? jg : NBANK - 1;
        clsS[tid] = class_label[jc];
        cluS[tid] = cluster_label[jc];
    }
    float4 a0 = *(const float4*)(gb);
    float4 a1 = *(const float4*)(gb + 4);
    float4 a2 = *(const float4*)(gb + 8);
    float4 a3 = *(const float4*)(gb + 12);

    // ---- Stage half 0 (slices 0..3). XOR-swizzle ^q: conflict-free (R3-verified 0).
    float sqa = 0.f;
    {
        s8 h, l;
        split8(a0, a1, h, l);
        sqa = sq8(a0, a1, sqa);
        int wi = (((sl_s * 4 + ct_s) * 64 + (p_s * 2 + 0) * 16 + cl_s)) ^ q;
        bHs[wi] = h; bLs[wi] = l;
        split8(a2, a3, h, l);
        sqa = sq8(a2, a3, sqa);
        wi = (((sl_s * 4 + ct_s) * 64 + (p_s * 2 + 1) * 16 + cl_s)) ^ q;
        bHs[wi] = h; bLs[wi] = l;
    }
    __syncthreads();                       // bar1: half-0 staged

    // ---- Issue half-1 loads NOW; land under compute0
    a0 = *(const float4*)(gb + 128);
    a1 = *(const float4*)(gb + 132);
    a2 = *(const float4*)(gb + 136);
    a3 = *(const float4*)(gb + 140);

    f32x4 acc[4][2];
    #pragma unroll
    for (int ct = 0; ct < 4; ++ct)
        #pragma unroll
        for (int rt = 0; rt < 2; ++rt)
            acc[ct][rt] = (f32x4){0.f, 0.f, 0.f, 0.f};

    // ---- Compute half 0: global slices 0..3
    #pragma unroll
    for (int sl = 0; sl < 4; ++sl) {
        s8 aH[2], aL[2];
        #pragma unroll
        for (int rt = 0; rt < 2; ++rt) {
            const int RT = w * 2 + rt;
            aH[rt] = fH[(RT * 8 + sl) * 64 + lane];
            aL[rt] = fL[(RT * 8 + sl) * 64 + lane];
        }
        const int rx = sl * 2 + (lane >> 5);           // read-side XOR (= writer's q)
        #pragma unroll
        for (int ct = 0; ct < 4; ++ct) {
            const s8 bh = bHs[((sl * 4 + ct) * 64 + lane) ^ rx];
            const s8 bl = bLs[((sl * 4 + ct) * 64 + lane) ^ rx];
            #pragma unroll
            for (int rt = 0; rt < 2; ++rt) {
                acc[ct][rt] = __builtin_amdgcn_mfma_f32_16x16x32_bf16(aH[rt], bh, acc[ct][rt], 0, 0, 0);
                acc[ct][rt] = __builtin_amdgcn_mfma_f32_16x16x32_bf16(aH[rt], bl, acc[ct][rt], 0, 0, 0);
                acc[ct][rt] = __builtin_amdgcn_mfma_f32_16x16x32_bf16(aL[rt], bh, acc[ct][rt], 0, 0, 0);
                acc[ct][rt] = __builtin_amdgcn_mfma_f32_16x16x32_bf16(aL[rt], bl, acc[ct][rt], 0, 0, 0);
            }
        }
    }
    __syncthreads();                       // bar2: all reads of half-0 LDS done

    // ---- Stage half 1 (slices 4..7 overwrite the same buffers)
    {
        s8 h, l;
        split8(a0, a1, h, l);
        sqa = sq8(a0, a1, sqa);
        int wi = (((sl_s * 4 + ct_s) * 64 + (p_s * 2 + 0) * 16 + cl_s)) ^ q;
        bHs[wi] = h; bLs[wi] = l;
        split8(a2, a3, h, l);
        sqa = sq8(a2, a3, sqa);
        wi = (((sl_s * 4 + ct_s) * 64 + (p_s * 2 + 1) * 16 + cl_s)) ^ q;
        bHs[wi] = h; bLs[wi] = l;
    }
    // ||b||^2 over full K: 8 q-threads of each col are adjacent lanes
    sqa += __shfl_xor(sqa, 1);
    sqa += __shfl_xor(sqa, 2);
    sqa += __shfl_xor(sqa, 4);
    if (q == 0) b2s[col] = sqa;
    __syncthreads();                       // bar3: half-1 staged, b2s visible

    // ---- Compute half 1: global slices 4..7
    #pragma unroll
    for (int sl = 0; sl < 4; ++sl) {
        s8 aH[2], aL[2];
        #pragma unroll
        for (int rt = 0; rt < 2; ++rt) {
            const int RT = w * 2 + rt;
            aH[rt] = fH[(RT * 8 + 4 + sl) * 64 + lane];
            aL[rt] = fL[(RT * 8 + 4 + sl) * 64 + lane];
        }
        const int rx = sl * 2 + (lane >> 5);
        #pragma unroll
        for (int ct = 0; ct < 4; ++ct) {
            const s8 bh = bHs[((sl * 4 + ct) * 64 + lane) ^ rx];
            const s8 bl = bLs[((sl * 4 + ct) * 64 + lane) ^ rx];
            #pragma unroll
            for (int rt = 0; rt < 2; ++rt) {
                acc[ct][rt] = __builtin_amdgcn_mfma_f32_16x16x32_bf16(aH[rt], bh, acc[ct][rt], 0, 0, 0);
                acc[ct][rt] = __builtin_amdgcn_mfma_f32_16x16x32_bf16(aH[rt], bl, acc[ct][rt], 0, 0, 0);
                acc[ct][rt] = __builtin_amdgcn_mfma_f32_16x16x32_bf16(aL[rt], bh, acc[ct][rt], 0, 0, 0);
                acc[ct][rt] = __builtin_amdgcn_mfma_f32_16x16x32_bf16(aL[rt], bl, acc[ct][rt], 0, 0, 0);
            }
        }
    }

    // ---- Epilogue: C/D layout col = lane&15, row = g*4 + reg (HW-verified)
    #pragma unroll
    for (int rt = 0; rt < 2; ++rt) {
        #pragma unroll
        for (int r = 0; r < 4; ++r) {
            const int row  = w * 32 + rt * 16 + g * 4 + r;
            const int myGt = rowGt[row], myClu = rowClu[row];
            float bpv = SENT, bdv = SENT;
            int   bpi = INT_MAX, bdi = INT_MAX;
            #pragma unroll
            for (int ct = 0; ct < 4; ++ct) {   // ascending ct = ascending col
                const int jg = j0 + ct * 16 + c;
                const float sc = b2s[ct * 16 + c] - 2.f * acc[ct][rt][r];
                if (jg < NBANK && clsS[ct * 16 + c] != myGt) {
                    if (sc < bdv) { bdv = sc; bdi = jg; }
                    if (cluS[ct * 16 + c] == myClu && sc < bpv) { bpv = sc; bpi = jg; }
                }
            }
            #pragma unroll
            for (int off = 1; off < 16; off <<= 1) {   // tie-aware 16-lane reduce
                float vv = __shfl_xor(bpv, off); int ii = __shfl_xor(bpi, off);
                if (vv < bpv || (vv == bpv && ii < bpi)) { bpv = vv; bpi = ii; }
                vv = __shfl_xor(bdv, off); ii = __shfl_xor(bdi, off);
                if (vv < bdv || (vv == bdv && ii < bdi)) { bdv = vv; bdi = ii; }
            }
            if (c == 0) {
                const size_t o = (size_t)jb * BQ + row;   // [jb][row]: 1KB runs
                wsPV[o] = bpv; wsPI[o] = bpi;
                wsDV[o] = bdv; wsDI[o] = bdi;
            }
        }
    }
}

// Kernel 2: per-row reduction over NJB partials (transposed layout), fallback
// select, gather bank row.
__global__ __launch_bounds__(256) void reduce_gather(
    const float* __restrict__ wsPV, const int* __restrict__ wsPI,
    const float* __restrict__ wsDV, const int* __restrict__ wsDI,
    const float* __restrict__ bank, float* __restrict__ out)
{
    const int row = blockIdx.x, tid = threadIdx.x;
    float bpv = SENT, bdv = SENT;
    int   bpi = INT_MAX, bdi = INT_MAX;
    for (int b = tid; b < NJB; b += 256) {
        const size_t o = (size_t)b * BQ + row;
        float v = wsPV[o]; int ix = wsPI[o];
        if (v < bpv || (v == bpv && ix < bpi)) { bpv = v; bpi = ix; }
        v = wsDV[o]; ix = wsDI[o];
        if (v < bdv || (v == bdv && ix < bdi)) { bdv = v; bdi = ix; }
    }
    #pragma unroll
    for (int off = 32; off > 0; off >>= 1) {
        float v = __shfl_down(bpv, off); int ix = __shfl_down(bpi, off);
        if (v < bpv || (v == bpv && ix < bpi)) { bpv = v; bpi = ix; }
        v = __shfl_down(bdv, off); ix = __shfl_down(bdi, off);
        if (v < bdv || (v == bdv && ix < bdi)) { bdv = v; bdi = ix; }
    }
    __shared__ float swPV[4], swDV[4];
    __shared__ int   swPI[4], swDI[4];
    __shared__ int   sIdx;
    const int lane = tid & 63, wv = tid >> 6;
    if (lane == 0) { swPV[wv] = bpv; swPI[wv] = bpi; swDV[wv] = bdv; swDI[wv] = bdi; }
    __syncthreads();
    if (tid == 0) {
        float pv = swPV[0]; int pi = swPI[0];
        float dv = swDV[0]; int di = swDI[0];
        #pragma unroll
        for (int w = 1; w < 4; ++w) {
            if (swPV[w] < pv || (swPV[w] == pv && swPI[w] < pi)) { pv = swPV[w]; pi = swPI[w]; }
            if (swDV[w] < dv || (swDV[w] == dv && swDI[w] < di)) { dv = swDV[w]; di = swDI[w]; }
        }
        sIdx = (pi != INT_MAX) ? pi : ((di != INT_MAX) ? di : 0);
    }
    __syncthreads();
    out[row * DDIM + tid] = bank[(size_t)sIdx * DDIM + tid];
}

extern "C" void kernel_launch(void* const* d_in, const int* in_sizes, int n_in,
                              void* d_out, int out_size, void* d_ws, size_t ws_size,
                              hipStream_t stream) {
    const float* feature       = (const float*)d_in[0];
    const float* bank          = (const float*)d_in[1];
    const int*   cluster_label = (const int*)d_in[2];
    const int*   class_label   = (const int*)d_in[3];
    const int*   cluster_idx   = (const int*)d_in[4];
    const int*   gt_label      = (const int*)d_in[5];
    float* out = (float*)d_out;

    // Workspace: fH/fL (128 KB each) + 4 partial arrays [NJB][256] (6.4 MB)
    s8* fH = (s8*)d_ws;                 // 8192 frags
    s8* fL = fH + 8192;
    float* base = (float*)((char*)d_ws + 2 * 8192 * sizeof(s8));
    const size_t per = (size_t)BQ * NJB;
    float* wsPV = base;
    int*   wsPI = (int*)base + per;
    float* wsDV = base + 2 * per;
    int*   wsDI = (int*)base + 3 * per;

    hipLaunchKernelGGL(split_feature, dim3(16), dim3(512), 0, stream, feature, fH, fL);
    hipLaunchKernelGGL(gemm_argmin_halfk, dim3(NJB), dim3(512), 0, stream,
                       fH, fL, bank, cluster_label, class_label, cluster_idx, gt_label,
                       wsPV, wsPI, wsDV, wsDI);
    hipLaunchKernelGGL(reduce_gather, dim3(BQ), dim3(256), 0, stream,
                       wsPV, wsPI, wsDV, wsDI, bank, out);
}

// Round 5
// 256.093 us; speedup vs baseline: 1.1742x; 1.1289x over previous
//
#include <hip/hip_runtime.h>
#include <climits>

typedef __attribute__((ext_vector_type(8))) short s8;      // 8 bf16 = 4 VGPRs
typedef __attribute__((ext_vector_type(4))) float f32x4;   // MFMA acc

#define BQ    256
#define DDIM  256
#define NBANK 100000
#define BN    64                          // bank cols per tile (4 col-tiles of 16)
#define NJB   ((NBANK + BN - 1) / BN)     // 1563
#define SENT  1e30f

// Split fp32 x into bf16 hi (round-half-up) + bf16 lo: x ~= hi + lo, |err| <~ 2^-18|x|
__device__ inline void splitElem(float x, s8& h, s8& l, int i) {
    unsigned u  = __float_as_uint(x);
    unsigned uh = (u + 0x8000u) & 0xFFFF0000u;
    h[i] = (short)(uh >> 16);
    float lf = x - __uint_as_float(uh);            // exact
    l[i] = (short)((__float_as_uint(lf) + 0x8000u) >> 16);
}

__device__ inline void split8(const float4 v0, const float4 v1, s8& h, s8& l) {
    splitElem(v0.x, h, l, 0); splitElem(v0.y, h, l, 1);
    splitElem(v0.z, h, l, 2); splitElem(v0.w, h, l, 3);
    splitElem(v1.x, h, l, 4); splitElem(v1.y, h, l, 5);
    splitElem(v1.z, h, l, 6); splitElem(v1.w, h, l, 7);
}

__device__ inline float sq8(const float4 v0, const float4 v1, float s) {
    s = fmaf(v0.x, v0.x, s); s = fmaf(v0.y, v0.y, s);
    s = fmaf(v0.z, v0.z, s); s = fmaf(v0.w, v0.w, s);
    s = fmaf(v1.x, v1.x, s); s = fmaf(v1.y, v1.y, s);
    s = fmaf(v1.z, v1.z, s); s = fmaf(v1.w, v1.w, s);
    return s;
}

// Kernel 0: pre-split the tiny A (feature) into MFMA-A-fragment-ordered bf16 hi/lo.
__global__ __launch_bounds__(512) void split_feature(
    const float* __restrict__ feature, s8* __restrict__ fH, s8* __restrict__ fL)
{
    const int t    = blockIdx.x * 512 + threadIdx.x;   // 0..8191
    const int lane = t & 63, ks = (t >> 6) & 7, rt = t >> 9;
    const int row  = rt * 16 + (lane & 15);
    const int k0   = ks * 32 + (lane >> 4) * 8;
    const float* p = feature + (size_t)row * DDIM + k0;
    const float4 v0 = *(const float4*)p;
    const float4 v1 = *(const float4*)(p + 4);
    s8 h, l;
    split8(v0, v1, h, l);
    fH[t] = h; fL[t] = l;
}

// Kernel 1: 1024-thread half-K split-bf16 MFMA GEMM + fused masked argmin.
// REGISTER-BUDGET-FIRST (R3: loop-carried arrays spill; R4: forced cap < live
// set spills 235 MB): 16 waves/block, each wave owns ONE 16-row tile ->
// acc[4]=16 VGPR; per-half lookahead = 8 floats = 8 VGPR. Peak live ~52 regs
// fits the 64-VGPR bucket honestly, so launch_bounds(1024,8) = 2 blocks/CU
// = 32 waves/CU (HW max) with NO spill. LDS ~35 KB (2 blocks = 70 KB fits).
// Pipeline: stage h0 | bar | issue h1 loads | compute h0 | bar | stage h1 |
// bar | compute h1 | epilogue.
__global__ __launch_bounds__(1024, 8) void gemm_argmin_w16(
    const s8* __restrict__ fH, const s8* __restrict__ fL,
    const float* __restrict__ bank,
    const int* __restrict__ cluster_label, const int* __restrict__ class_label,
    const int* __restrict__ cluster_idx,  const int* __restrict__ gt_label,
    float* __restrict__ wsPV, int* __restrict__ wsPI,
    float* __restrict__ wsDV, int* __restrict__ wsDI)
{
    __shared__ __align__(16) s8 bHs[4 * 4 * 64];   // [sl][ct][fraglane] 16 KB
    __shared__ __align__(16) s8 bLs[4 * 4 * 64];   // 16 KB
    __shared__ float b2s[BN];
    __shared__ int clsS[BN], cluS[BN], rowGt[BQ], rowClu[BQ];

    const int tid = threadIdx.x;
    const int jb  = blockIdx.x;
    const int j0  = jb * BN;

    // Staging role: col = tid>>4 (0..63), q = tid&15; per half: one 8-float octet
    const int col = tid >> 4, q = tid & 15;
    const int ct_s = col >> 4, cl_s = col & 15;
    const int sl_s = q >> 2, o_s = q & 3;          // slice-in-half, octet-in-slice
    // Compute/epilogue role: wave w (0..15) owns row-tile w
    const int w = tid >> 6, lane = tid & 63;
    const int g = lane >> 4, c = lane & 15;

    int jcol = j0 + col; if (jcol >= NBANK) jcol = NBANK - 1;
    const float* gb = bank + (size_t)jcol * DDIM + q * 8;    // +128 for half 1

    // ---- Prologue: labels + half-0 loads (8 floats/thread)
    if (tid < BQ) {
        rowGt[tid]  = gt_label[tid];
        rowClu[tid] = cluster_idx[tid];
    }
    if (tid < BN) {
        int jg = j0 + tid; int jc = jg < NBANK ? jg : NBANK - 1;
        clsS[tid] = class_label[jc];
        cluS[tid] = cluster_label[jc];
    }
    float4 a0 = *(const float4*)(gb);
    float4 a1 = *(const float4*)(gb + 4);

    // ---- Stage half 0 (slices 0..3). Writer XOR ^q: quarter-wave (16 lanes,
    // same col) spreads across all 8 bank-quads 2-way = conflict-free.
    float sqa = 0.f;
    {
        s8 h, l;
        split8(a0, a1, h, l);
        sqa = sq8(a0, a1, sqa);
        const int wi = (((sl_s * 4 + ct_s) * 64 + o_s * 16 + cl_s)) ^ q;
        bHs[wi] = h; bLs[wi] = l;
    }
    __syncthreads();                       // bar1: half-0 staged

    // ---- Issue half-1 loads NOW; land under compute-h0 (only 8 VGPRs held)
    a0 = *(const float4*)(gb + 128);
    a1 = *(const float4*)(gb + 132);

    f32x4 acc[4];
    #pragma unroll
    for (int ct = 0; ct < 4; ++ct)
        acc[ct] = (f32x4){0.f, 0.f, 0.f, 0.f};

    // ---- Compute half 0: global slices 0..3; 64 MFMAs/wave per half
    #pragma unroll
    for (int sl = 0; sl < 4; ++sl) {
        const s8 aH = fH[(w * 8 + sl) * 64 + lane];
        const s8 aL = fL[(w * 8 + sl) * 64 + lane];
        const int rx = sl * 4 + g;                  // = writer's q for this slot
        #pragma unroll
        for (int ct = 0; ct < 4; ++ct) {
            const s8 bh = bHs[((sl * 4 + ct) * 64 + lane) ^ rx];
            const s8 bl = bLs[((sl * 4 + ct) * 64 + lane) ^ rx];
            acc[ct] = __builtin_amdgcn_mfma_f32_16x16x32_bf16(aH, bh, acc[ct], 0, 0, 0);
            acc[ct] = __builtin_amdgcn_mfma_f32_16x16x32_bf16(aH, bl, acc[ct], 0, 0, 0);
            acc[ct] = __builtin_amdgcn_mfma_f32_16x16x32_bf16(aL, bh, acc[ct], 0, 0, 0);
            acc[ct] = __builtin_amdgcn_mfma_f32_16x16x32_bf16(aL, bl, acc[ct], 0, 0, 0);
        }
    }
    __syncthreads();                       // bar2: all reads of half-0 LDS done

    // ---- Stage half 1 (slices 4..7 overwrite the same buffers)
    {
        s8 h, l;
        split8(a0, a1, h, l);
        sqa = sq8(a0, a1, sqa);
        const int wi = (((sl_s * 4 + ct_s) * 64 + o_s * 16 + cl_s)) ^ q;
        bHs[wi] = h; bLs[wi] = l;
    }
    // ||b||^2 over full K: the 16 q-threads of each col are adjacent lanes
    sqa += __shfl_xor(sqa, 1);
    sqa += __shfl_xor(sqa, 2);
    sqa += __shfl_xor(sqa, 4);
    sqa += __shfl_xor(sqa, 8);
    if (q == 0) b2s[col] = sqa;
    __syncthreads();                       // bar3: half-1 staged, b2s visible

    // ---- Compute half 1: global slices 4..7
    #pragma unroll
    for (int sl = 0; sl < 4; ++sl) {
        const s8 aH = fH[(w * 8 + 4 + sl) * 64 + lane];
        const s8 aL = fL[(w * 8 + 4 + sl) * 64 + lane];
        const int rx = sl * 4 + g;
        #pragma unroll
        for (int ct = 0; ct < 4; ++ct) {
            const s8 bh = bHs[((sl * 4 + ct) * 64 + lane) ^ rx];
            const s8 bl = bLs[((sl * 4 + ct) * 64 + lane) ^ rx];
            acc[ct] = __builtin_amdgcn_mfma_f32_16x16x32_bf16(aH, bh, acc[ct], 0, 0, 0);
            acc[ct] = __builtin_amdgcn_mfma_f32_16x16x32_bf16(aH, bl, acc[ct], 0, 0, 0);
            acc[ct] = __builtin_amdgcn_mfma_f32_16x16x32_bf16(aL, bh, acc[ct], 0, 0, 0);
            acc[ct] = __builtin_amdgcn_mfma_f32_16x16x32_bf16(aL, bl, acc[ct], 0, 0, 0);
        }
    }

    // ---- Epilogue: C/D layout col = lane&15, row = g*4 + reg (HW-verified)
    #pragma unroll
    for (int r = 0; r < 4; ++r) {
        const int row  = w * 16 + g * 4 + r;
        const int myGt = rowGt[row], myClu = rowClu[row];
        float bpv = SENT, bdv = SENT;
        int   bpi = INT_MAX, bdi = INT_MAX;
        #pragma unroll
        for (int ct = 0; ct < 4; ++ct) {   // ascending ct = ascending col per lane
            const int jg = j0 + ct * 16 + c;
            const float sc = b2s[ct * 16 + c] - 2.f * acc[ct][r];
            if (jg < NBANK && clsS[ct * 16 + c] != myGt) {
                if (sc < bdv) { bdv = sc; bdi = jg; }
                if (cluS[ct * 16 + c] == myClu && sc < bpv) { bpv = sc; bpi = jg; }
            }
        }
        #pragma unroll
        for (int off = 1; off < 16; off <<= 1) {   // tie-aware 16-lane reduce
            float vv = __shfl_xor(bpv, off); int ii = __shfl_xor(bpi, off);
            if (vv < bpv || (vv == bpv && ii < bpi)) { bpv = vv; bpi = ii; }
            vv = __shfl_xor(bdv, off); ii = __shfl_xor(bdi, off);
            if (vv < bdv || (vv == bdv && ii < bdi)) { bdv = vv; bdi = ii; }
        }
        if (c == 0) {
            const size_t o = (size_t)jb * BQ + row;   // [jb][row]: 1 KB runs
            wsPV[o] = bpv; wsPI[o] = bpi;
            wsDV[o] = bdv; wsDI[o] = bdi;
        }
    }
}

// Kernel 2: per-row reduction over NJB partials (transposed layout), fallback
// select, gather bank row.
__global__ __launch_bounds__(256) void reduce_gather(
    const float* __restrict__ wsPV, const int* __restrict__ wsPI,
    const float* __restrict__ wsDV, const int* __restrict__ wsDI,
    const float* __restrict__ bank, float* __restrict__ out)
{
    const int row = blockIdx.x, tid = threadIdx.x;
    float bpv = SENT, bdv = SENT;
    int   bpi = INT_MAX, bdi = INT_MAX;
    for (int b = tid; b < NJB; b += 256) {
        const size_t o = (size_t)b * BQ + row;
        float v = wsPV[o]; int ix = wsPI[o];
        if (v < bpv || (v == bpv && ix < bpi)) { bpv = v; bpi = ix; }
        v = wsDV[o]; ix = wsDI[o];
        if (v < bdv || (v == bdv && ix < bdi)) { bdv = v; bdi = ix; }
    }
    #pragma unroll
    for (int off = 32; off > 0; off >>= 1) {
        float v = __shfl_down(bpv, off); int ix = __shfl_down(bpi, off);
        if (v < bpv || (v == bpv && ix < bpi)) { bpv = v; bpi = ix; }
        v = __shfl_down(bdv, off); ix = __shfl_down(bdi, off);
        if (v < bdv || (v == bdv && ix < bdi)) { bdv = v; bdi = ix; }
    }
    __shared__ float swPV[4], swDV[4];
    __shared__ int   swPI[4], swDI[4];
    __shared__ int   sIdx;
    const int lane = tid & 63, wv = tid >> 6;
    if (lane == 0) { swPV[wv] = bpv; swPI[wv] = bpi; swDV[wv] = bdv; swDI[wv] = bdi; }
    __syncthreads();
    if (tid == 0) {
        float pv = swPV[0]; int pi = swPI[0];
        float dv = swDV[0]; int di = swDI[0];
        #pragma unroll
        for (int w = 1; w < 4; ++w) {
            if (swPV[w] < pv || (swPV[w] == pv && swPI[w] < pi)) { pv = swPV[w]; pi = swPI[w]; }
            if (swDV[w] < dv || (swDV[w] == dv && swDI[w] < di)) { dv = swDV[w]; di = swDI[w]; }
        }
        sIdx = (pi != INT_MAX) ? pi : ((di != INT_MAX) ? di : 0);
    }
    __syncthreads();
    out[row * DDIM + tid] = bank[(size_t)sIdx * DDIM + tid];
}

extern "C" void kernel_launch(void* const* d_in, const int* in_sizes, int n_in,
                              void* d_out, int out_size, void* d_ws, size_t ws_size,
                              hipStream_t stream) {
    const float* feature       = (const float*)d_in[0];
    const float* bank          = (const float*)d_in[1];
    const int*   cluster_label = (const int*)d_in[2];
    const int*   class_label   = (const int*)d_in[3];
    const int*   cluster_idx   = (const int*)d_in[4];
    const int*   gt_label      = (const int*)d_in[5];
    float* out = (float*)d_out;

    // Workspace: fH/fL (128 KB each) + 4 partial arrays [NJB][256] (6.4 MB)
    s8* fH = (s8*)d_ws;                 // 8192 frags
    s8* fL = fH + 8192;
    float* base = (float*)((char*)d_ws + 2 * 8192 * sizeof(s8));
    const size_t per = (size_t)BQ * NJB;
    float* wsPV = base;
    int*   wsPI = (int*)base + per;
    float* wsDV = base + 2 * per;
    int*   wsDI = (int*)base + 3 * per;

    hipLaunchKernelGGL(split_feature, dim3(16), dim3(512), 0, stream, feature, fH, fL);
    hipLaunchKernelGGL(gemm_argmin_w16, dim3(NJB), dim3(1024), 0, stream,
                       fH, fL, bank, cluster_label, class_label, cluster_idx, gt_label,
                       wsPV, wsPI, wsDV, wsDI);
    hipLaunchKernelGGL(reduce_gather, dim3(BQ), dim3(256), 0, stream,
                       wsPV, wsPI, wsDV, wsDI, bank, out);
}

// Round 6
// 230.134 us; speedup vs baseline: 1.3067x; 1.1128x over previous
//
#include <hip/hip_runtime.h>
#include <climits>

typedef __attribute__((ext_vector_type(8))) short s8;      // 8 bf16 = 4 VGPRs
typedef __attribute__((ext_vector_type(4))) float f32x4;   // MFMA acc

#define BQ    256
#define DDIM  256
#define NBANK 100000
#define BN    64                          // bank cols per tile (4 col-tiles of 16)
#define NJB   ((NBANK + BN - 1) / BN)     // 1563
#define SENT  1e30f

// Split fp32 x into bf16 hi (round-half-up) + bf16 lo: x ~= hi + lo, |err| <~ 2^-18|x|
__device__ inline void splitElem(float x, s8& h, s8& l, int i) {
    unsigned u  = __float_as_uint(x);
    unsigned uh = (u + 0x8000u) & 0xFFFF0000u;
    h[i] = (short)(uh >> 16);
    float lf = x - __uint_as_float(uh);            // exact
    l[i] = (short)((__float_as_uint(lf) + 0x8000u) >> 16);
}

__device__ inline void split8(const float4 v0, const float4 v1, s8& h, s8& l) {
    splitElem(v0.x, h, l, 0); splitElem(v0.y, h, l, 1);
    splitElem(v0.z, h, l, 2); splitElem(v0.w, h, l, 3);
    splitElem(v1.x, h, l, 4); splitElem(v1.y, h, l, 5);
    splitElem(v1.z, h, l, 6); splitElem(v1.w, h, l, 7);
}

__device__ inline float sq8(const float4 v0, const float4 v1, float s) {
    s = fmaf(v0.x, v0.x, s); s = fmaf(v0.y, v0.y, s);
    s = fmaf(v0.z, v0.z, s); s = fmaf(v0.w, v0.w, s);
    s = fmaf(v1.x, v1.x, s); s = fmaf(v1.y, v1.y, s);
    s = fmaf(v1.z, v1.z, s); s = fmaf(v1.w, v1.w, s);
    return s;
}

// Kernel 0: pre-split the tiny A (feature) into MFMA-A-fragment-ordered bf16 hi/lo.
__global__ __launch_bounds__(512) void split_feature(
    const float* __restrict__ feature, s8* __restrict__ fH, s8* __restrict__ fL)
{
    const int t    = blockIdx.x * 512 + threadIdx.x;   // 0..8191
    const int lane = t & 63, ks = (t >> 6) & 7, rt = t >> 9;
    const int row  = rt * 16 + (lane & 15);
    const int k0   = ks * 32 + (lane >> 4) * 8;
    const float* p = feature + (size_t)row * DDIM + k0;
    const float4 v0 = *(const float4*)p;
    const float4 v1 = *(const float4*)(p + 4);
    s8 h, l;
    split8(v0, v1, h, l);
    fH[t] = h; fL[t] = l;
}

// Kernel 1: M-SPLIT half-K split-bf16 MFMA GEMM + fused masked argmin.
// Register-pressure lesson (R4/R5: ANY forced 64-reg budget makes the unified
// VGPR/AGPR allocator pin arch regs at 32 and spill 100-300 MB to scratch):
// do NOT cap tight. launch_bounds(512,4) = 128-reg cap (R2-proven spill-free);
// the small live set comes structurally: 8 waves/block, each wave owns ONE
// 16-row tile (acc[4] = 16 accs), blocks M-split (grid = NJB*2, mh = rows
// 0-127 / 128-255 of the same bank tile). Half-K LDS ~35 KB -> up to 4
// blocks/CU by LDS; occupancy lands by whatever reg bucket the compiler
// honestly needs (64 -> 32 waves/CU, 85 -> 24 waves/CU). B tile staged twice
// (once per M-half) - extra L2/VALU only; bank is L3-resident so HBM is flat.
// Pipeline per block: stage h0 | bar | issue h1 loads | compute h0 | bar |
// stage h1 | bar | compute h1 | epilogue. Swizzle = R4's (0 conflicts).
__global__ __launch_bounds__(512, 4) void gemm_argmin_msplit(
    const s8* __restrict__ fH, const s8* __restrict__ fL,
    const float* __restrict__ bank,
    const int* __restrict__ cluster_label, const int* __restrict__ class_label,
    const int* __restrict__ cluster_idx,  const int* __restrict__ gt_label,
    float* __restrict__ wsPV, int* __restrict__ wsPI,
    float* __restrict__ wsDV, int* __restrict__ wsDI)
{
    __shared__ __align__(16) s8 bHs[4 * 4 * 64];   // [sl][ct][fraglane] 16 KB
    __shared__ __align__(16) s8 bLs[4 * 4 * 64];   // 16 KB
    __shared__ float b2s[BN];
    __shared__ int clsS[BN], cluS[BN], rowGt[128], rowClu[128];

    const int tid = threadIdx.x;
    const int bb  = blockIdx.x;
    const int jb  = bb >> 1, mh = bb & 1;          // bank tile, M-half
    const int j0  = jb * BN;
    const int r0  = mh * 128;

    // Staging role: col = tid>>3 (0..63), q = tid&7; per half: two 8-float octets
    const int col = tid >> 3, q = tid & 7;
    const int ct_s = col >> 4, cl_s = col & 15;
    const int sl_s = q >> 1, p_s = q & 1;          // slice-in-half, octet-pair
    // Compute/epilogue role: wave w (0..7) owns global row-tile mh*8 + w
    const int w = tid >> 6, lane = tid & 63;
    const int g = lane >> 4, c = lane & 15;

    int jcol = j0 + col; if (jcol >= NBANK) jcol = NBANK - 1;
    const float* gb = bank + (size_t)jcol * DDIM + q * 16;   // +128 for half 1

    // ---- Prologue: labels + half-0 loads (16 floats/thread)
    if (tid < 128) {
        rowGt[tid]  = gt_label[r0 + tid];
        rowClu[tid] = cluster_idx[r0 + tid];
    }
    if (tid < BN) {
        int jg = j0 + tid; int jc = jg < NBANK ? jg : NBANK - 1;
        clsS[tid] = class_label[jc];
        cluS[tid] = cluster_label[jc];
    }
    float4 a0 = *(const float4*)(gb);
    float4 a1 = *(const float4*)(gb + 4);
    float4 a2 = *(const float4*)(gb + 8);
    float4 a3 = *(const float4*)(gb + 12);

    // ---- Stage half 0 (slices 0..3). Writer XOR ^q (R4-verified: 0 conflicts).
    float sqa = 0.f;
    {
        s8 h, l;
        split8(a0, a1, h, l);
        sqa = sq8(a0, a1, sqa);
        int wi = (((sl_s * 4 + ct_s) * 64 + (p_s * 2 + 0) * 16 + cl_s)) ^ q;
        bHs[wi] = h; bLs[wi] = l;
        split8(a2, a3, h, l);
        sqa = sq8(a2, a3, sqa);
        wi = (((sl_s * 4 + ct_s) * 64 + (p_s * 2 + 1) * 16 + cl_s)) ^ q;
        bHs[wi] = h; bLs[wi] = l;
    }
    __syncthreads();                       // bar1: half-0 staged

    // ---- Issue half-1 loads NOW; land under compute-h0 (16 VGPRs held)
    a0 = *(const float4*)(gb + 128);
    a1 = *(const float4*)(gb + 132);
    a2 = *(const float4*)(gb + 136);
    a3 = *(const float4*)(gb + 140);

    f32x4 acc[4];
    #pragma unroll
    for (int ct = 0; ct < 4; ++ct)
        acc[ct] = (f32x4){0.f, 0.f, 0.f, 0.f};

    const int RT = mh * 8 + w;                     // this wave's global row-tile

    // ---- Compute half 0: global slices 0..3; 64 MFMAs/wave
    #pragma unroll
    for (int sl = 0; sl < 4; ++sl) {
        const s8 aH = fH[(RT * 8 + sl) * 64 + lane];
        const s8 aL = fL[(RT * 8 + sl) * 64 + lane];
        const int rx = sl * 2 + (lane >> 5);       // = writer's q for this slot
        #pragma unroll
        for (int ct = 0; ct < 4; ++ct) {
            const s8 bh = bHs[((sl * 4 + ct) * 64 + lane) ^ rx];
            const s8 bl = bLs[((sl * 4 + ct) * 64 + lane) ^ rx];
            acc[ct] = __builtin_amdgcn_mfma_f32_16x16x32_bf16(aH, bh, acc[ct], 0, 0, 0);
            acc[ct] = __builtin_amdgcn_mfma_f32_16x16x32_bf16(aH, bl, acc[ct], 0, 0, 0);
            acc[ct] = __builtin_amdgcn_mfma_f32_16x16x32_bf16(aL, bh, acc[ct], 0, 0, 0);
            acc[ct] = __builtin_amdgcn_mfma_f32_16x16x32_bf16(aL, bl, acc[ct], 0, 0, 0);
        }
    }
    __syncthreads();                       // bar2: all reads of half-0 LDS done

    // ---- Stage half 1 (slices 4..7 overwrite the same buffers)
    {
        s8 h, l;
        split8(a0, a1, h, l);
        sqa = sq8(a0, a1, sqa);
        int wi = (((sl_s * 4 + ct_s) * 64 + (p_s * 2 + 0) * 16 + cl_s)) ^ q;
        bHs[wi] = h; bLs[wi] = l;
        split8(a2, a3, h, l);
        sqa = sq8(a2, a3, sqa);
        wi = (((sl_s * 4 + ct_s) * 64 + (p_s * 2 + 1) * 16 + cl_s)) ^ q;
        bHs[wi] = h; bLs[wi] = l;
    }
    // ||b||^2 over full K: 8 q-threads of each col are adjacent lanes
    sqa += __shfl_xor(sqa, 1);
    sqa += __shfl_xor(sqa, 2);
    sqa += __shfl_xor(sqa, 4);
    if (q == 0) b2s[col] = sqa;
    __syncthreads();                       // bar3: half-1 staged, b2s visible

    // ---- Compute half 1: global slices 4..7
    #pragma unroll
    for (int sl = 0; sl < 4; ++sl) {
        const s8 aH = fH[(RT * 8 + 4 + sl) * 64 + lane];
        const s8 aL = fL[(RT * 8 + 4 + sl) * 64 + lane];
        const int rx = sl * 2 + (lane >> 5);
        #pragma unroll
        for (int ct = 0; ct < 4; ++ct) {
            const s8 bh = bHs[((sl * 4 + ct) * 64 + lane) ^ rx];
            const s8 bl = bLs[((sl * 4 + ct) * 64 + lane) ^ rx];
            acc[ct] = __builtin_amdgcn_mfma_f32_16x16x32_bf16(aH, bh, acc[ct], 0, 0, 0);
            acc[ct] = __builtin_amdgcn_mfma_f32_16x16x32_bf16(aH, bl, acc[ct], 0, 0, 0);
            acc[ct] = __builtin_amdgcn_mfma_f32_16x16x32_bf16(aL, bh, acc[ct], 0, 0, 0);
            acc[ct] = __builtin_amdgcn_mfma_f32_16x16x32_bf16(aL, bl, acc[ct], 0, 0, 0);
        }
    }

    // ---- Epilogue: C/D layout col = lane&15, row = g*4 + reg (HW-verified)
    #pragma unroll
    for (int r = 0; r < 4; ++r) {
        const int lrow = w * 16 + g * 4 + r;       // 0..127 within this M-half
        const int myGt = rowGt[lrow], myClu = rowClu[lrow];
        float bpv = SENT, bdv = SENT;
        int   bpi = INT_MAX, bdi = INT_MAX;
        #pragma unroll
        for (int ct = 0; ct < 4; ++ct) {   // ascending ct = ascending col per lane
            const int jg = j0 + ct * 16 + c;
            const float sc = b2s[ct * 16 + c] - 2.f * acc[ct][r];
            if (jg < NBANK && clsS[ct * 16 + c] != myGt) {
                if (sc < bdv) { bdv = sc; bdi = jg; }
                if (cluS[ct * 16 + c] == myClu && sc < bpv) { bpv = sc; bpi = jg; }
            }
        }
        #pragma unroll
        for (int off = 1; off < 16; off <<= 1) {   // tie-aware 16-lane reduce
            float vv = __shfl_xor(bpv, off); int ii = __shfl_xor(bpi, off);
            if (vv < bpv || (vv == bpv && ii < bpi)) { bpv = vv; bpi = ii; }
            vv = __shfl_xor(bdv, off); ii = __shfl_xor(bdi, off);
            if (vv < bdv || (vv == bdv && ii < bdi)) { bdv = vv; bdi = ii; }
        }
        if (c == 0) {
            const size_t o = (size_t)jb * BQ + r0 + lrow;   // [jb][row]: 1 KB runs
            wsPV[o] = bpv; wsPI[o] = bpi;
            wsDV[o] = bdv; wsDI[o] = bdi;
        }
    }
}

// Kernel 2: per-row reduction over NJB partials (transposed layout), fallback
// select, gather bank row.
__global__ __launch_bounds__(256) void reduce_gather(
    const float* __restrict__ wsPV, const int* __restrict__ wsPI,
    const float* __restrict__ wsDV, const int* __restrict__ wsDI,
    const float* __restrict__ bank, float* __restrict__ out)
{
    const int row = blockIdx.x, tid = threadIdx.x;
    float bpv = SENT, bdv = SENT;
    int   bpi = INT_MAX, bdi = INT_MAX;
    for (int b = tid; b < NJB; b += 256) {
        const size_t o = (size_t)b * BQ + row;
        float v = wsPV[o]; int ix = wsPI[o];
        if (v < bpv || (v == bpv && ix < bpi)) { bpv = v; bpi = ix; }
        v = wsDV[o]; ix = wsDI[o];
        if (v < bdv || (v == bdv && ix < bdi)) { bdv = v; bdi = ix; }
    }
    #pragma unroll
    for (int off = 32; off > 0; off >>= 1) {
        float v = __shfl_down(bpv, off); int ix = __shfl_down(bpi, off);
        if (v < bpv || (v == bpv && ix < bpi)) { bpv = v; bpi = ix; }
        v = __shfl_down(bdv, off); ix = __shfl_down(bdi, off);
        if (v < bdv || (v == bdv && ix < bdi)) { bdv = v; bdi = ix; }
    }
    __shared__ float swPV[4], swDV[4];
    __shared__ int   swPI[4], swDI[4];
    __shared__ int   sIdx;
    const int lane = tid & 63, wv = tid >> 6;
    if (lane == 0) { swPV[wv] = bpv; swPI[wv] = bpi; swDV[wv] = bdv; swDI[wv] = bdi; }
    __syncthreads();
    if (tid == 0) {
        float pv = swPV[0]; int pi = swPI[0];
        float dv = swDV[0]; int di = swDI[0];
        #pragma unroll
        for (int w = 1; w < 4; ++w) {
            if (swPV[w] < pv || (swPV[w] == pv && swPI[w] < pi)) { pv = swPV[w]; pi = swPI[w]; }
            if (swDV[w] < dv || (swDV[w] == dv && swDI[w] < di)) { dv = swDV[w]; di = swDI[w]; }
        }
        sIdx = (pi != INT_MAX) ? pi : ((di != INT_MAX) ? di : 0);
    }
    __syncthreads();
    out[row * DDIM + tid] = bank[(size_t)sIdx * DDIM + tid];
}

extern "C" void kernel_launch(void* const* d_in, const int* in_sizes, int n_in,
                              void* d_out, int out_size, void* d_ws, size_t ws_size,
                              hipStream_t stream) {
    const float* feature       = (const float*)d_in[0];
    const float* bank          = (const float*)d_in[1];
    const int*   cluster_label = (const int*)d_in[2];
    const int*   class_label   = (const int*)d_in[3];
    const int*   cluster_idx   = (const int*)d_in[4];
    const int*   gt_label      = (const int*)d_in[5];
    float* out = (float*)d_out;

    // Workspace: fH/fL (128 KB each) + 4 partial arrays [NJB][256] (6.4 MB)
    s8* fH = (s8*)d_ws;                 // 8192 frags
    s8* fL = fH + 8192;
    float* base = (float*)((char*)d_ws + 2 * 8192 * sizeof(s8));
    const size_t per = (size_t)BQ * NJB;
    float* wsPV = base;
    int*   wsPI = (int*)base + per;
    float* wsDV = base + 2 * per;
    int*   wsDI = (int*)base + 3 * per;

    hipLaunchKernelGGL(split_feature, dim3(16), dim3(512), 0, stream, feature, fH, fL);
    hipLaunchKernelGGL(gemm_argmin_msplit, dim3(NJB * 2), dim3(512), 0, stream,
                       fH, fL, bank, cluster_label, class_label, cluster_idx, gt_label,
                       wsPV, wsPI, wsDV, wsDI);
    hipLaunchKernelGGL(reduce_gather, dim3(BQ), dim3(256), 0, stream,
                       wsPV, wsPI, wsDV, wsDI, bank, out);
}